// Round 7
// baseline (263.597 us; speedup 1.0000x reference)
//
#include <hip/hip_runtime.h>

#define BB 4
#define SS 2048
#define EE 1024

typedef _Float16 f16;
typedef _Float16 f16x4 __attribute__((ext_vector_type(4)));
typedef _Float16 f16x8 __attribute__((ext_vector_type(8)));
typedef float f32x4 __attribute__((ext_vector_type(4)));

typedef const __attribute__((address_space(1))) void* gas_ptr;
typedef __attribute__((address_space(3))) void* las_ptr;

__device__ __forceinline__ void gl_lds16(const void* g, void* l) {
  __builtin_amdgcn_global_load_lds((gas_ptr)g, (las_ptr)l, 16, 0, 0);
}

#define BAR() __builtin_amdgcn_s_barrier()
#define PRIO1() __builtin_amdgcn_s_setprio(1)
#define PRIO0() __builtin_amdgcn_s_setprio(0)
#define WAITV6() asm volatile("s_waitcnt vmcnt(6)" ::: "memory")
#define WAITV0() asm volatile("s_waitcnt vmcnt(0)" ::: "memory")

// ---------- prep: per-batch mask prefix-scan + pad-row zeroing ----------
__global__ __launch_bounds__(256) void prep(const int* __restrict__ mask,
                                            int* __restrict__ pos,
                                            int2* __restrict__ cnt,
                                            f16* __restrict__ Kc,
                                            f16* __restrict__ Vc) {
  const int b = blockIdx.x, t = threadIdx.x;
  const int* mb = mask + b * SS;
  int4 a0 = ((const int4*)mb)[t * 2];
  int4 a1 = ((const int4*)mb)[t * 2 + 1];
  int m[8] = {a0.x, a0.y, a0.z, a0.w, a1.x, a1.y, a1.z, a1.w};
  int tot = 0;
#pragma unroll
  for (int j = 0; j < 8; ++j) tot += m[j];
  __shared__ int sc[256];
  sc[t] = tot;
  __syncthreads();
  for (int off = 1; off < 256; off <<= 1) {
    int v = (t >= off) ? sc[t - off] : 0;
    __syncthreads();
    sc[t] += v;
    __syncthreads();
  }
  const int count = sc[255];
  const int padded = (count + 127) & ~127;
  int run = sc[t] - tot;  // exclusive prefix
#pragma unroll
  for (int j = 0; j < 8; ++j) {
    pos[b * SS + t * 8 + j] = run;
    run += m[j];
  }
  if (t == 0) cnt[b] = make_int2(count, padded);
  const int nz = (padded - count) * 128;
  f16x8 z = {};
  for (int i = t; i < nz; i += 256) {
    int r = count + (i >> 7), cc = i & 127;
    ((f16x8*)(Kc + ((long)b * SS + r) * EE))[cc] = z;
    ((f16x8*)(Vc + ((long)b * SS + r) * EE))[cc] = z;
  }
}

// ---------- prep2: Q/W cvt, zero rowsum+done, XCD item-list build, gather ----------
__global__ __launch_bounds__(256) void prep2(const float* __restrict__ Q,
                                             const float* __restrict__ W,
                                             const float* __restrict__ K,
                                             const float* __restrict__ V,
                                             const int* __restrict__ mask,
                                             const int* __restrict__ pos,
                                             const int2* __restrict__ cnt,
                                             f16* __restrict__ Qh,
                                             f16* __restrict__ Wh,
                                             f16* __restrict__ Kc,
                                             f16* __restrict__ Vc,
                                             float* __restrict__ rowsum,
                                             int* __restrict__ items,
                                             int* __restrict__ nit,
                                             int* __restrict__ done) {
  const int x = blockIdx.x, t = threadIdx.x;
  if (x < 4608) {  // Q cvt (x<4096) or W cvt
    const float* in = (x < 4096) ? Q : W;
    f16* out = (x < 4096) ? Qh : Wh;
    long i = (long)(x < 4096 ? x : x - 4096) * 256 + t;
    float4 v0 = ((const float4*)in)[i * 2];
    float4 v1 = ((const float4*)in)[i * 2 + 1];
    f16x8 o;
    o[0] = (f16)v0.x; o[1] = (f16)v0.y; o[2] = (f16)v0.z; o[3] = (f16)v0.w;
    o[4] = (f16)v1.x; o[5] = (f16)v1.y; o[6] = (f16)v1.z; o[7] = (f16)v1.w;
    ((f16x8*)out)[i] = o;
    return;
  }
  if (x == 4608) {  // zero rowsum[B*S] + done[48]
    float4 z = {0.f, 0.f, 0.f, 0.f};
#pragma unroll
    for (int r = 0; r < 8; ++r) ((float4*)rowsum)[t + r * 256] = z;
    if (t < 48) done[t] = 0;
    return;
  }
  if (x == 4609) {  // build per-XCD interleaved item list (8 threads)
    if (t < 8) {
      int nbx[4];
#pragma unroll
      for (int zz = 0; zz < 4; ++zz) nbx[zz] = cnt[zz].y >> 7;
      const int sq = nbx[0] + nbx[1] + nbx[2] + nbx[3];
      const int p02 = nbx[0] + nbx[2], p13 = nbx[1] + nbx[3];
      const int mx = sq + (p02 > p13 ? p02 : p13) + 32;
      int g = 0;
      // QK: A-panel by = t (this XCD's M-row), grouped by batch
      for (int zz = 0; zz < 4; ++zz)
        for (int bx = 0; bx < nbx[zz]; ++bx)
          items[(g++ << 3) | t] = bx | (t << 8) | (zz << 16);
      // WV: byW = t&3, batches {t>>2, 2+(t>>2)}
      for (int h = 0; h < 2; ++h) {
        int zz = (t >> 2) + 2 * h;
        for (int bx = 0; bx < nbx[zz]; ++bx)
          items[(g++ << 3) | t] = bx | ((t & 3) << 8) | (zz << 16) | (1 << 24);
      }
      // PV: byM = t, all 8 E-panels, grouped by batch
      for (int zz = 0; zz < 4; ++zz)
        for (int be = 0; be < 8; ++be)
          items[(g++ << 3) | t] = be | (t << 8) | (zz << 16) | (2 << 24);
      for (; g < mx; ++g) items[(g << 3) | t] = (3 << 24);  // skip pad
      if (t == 0) nit[0] = mx << 3;
    }
    return;
  }
  // gather: masked K/V rows -> compacted f16
  const int r = x - 4610, b = r >> 11, s = r & (SS - 1);
  if (!mask[b * SS + s]) return;
  const int p = pos[b * SS + s];
  float4 kv = ((const float4*)(K + ((long)b * SS + s) * EE))[t];
  float4 vv = ((const float4*)(V + ((long)b * SS + s) * EE))[t];
  f16x4 ko, vo;
  ko[0] = (f16)kv.x; ko[1] = (f16)kv.y; ko[2] = (f16)kv.z; ko[3] = (f16)kv.w;
  vo[0] = (f16)vv.x; vo[1] = (f16)vv.y; vo[2] = (f16)vv.z; vo[3] = (f16)vv.w;
  ((f16x4*)(Kc + ((long)b * SS + p) * EE))[t] = ko;
  ((f16x4*)(Vc + ((long)b * SS + p) * EE))[t] = vo;
}

// ---------- shared 256x128 8-phase GEMM core (R6-verified, unchanged) ----------
__device__ __forceinline__ void stage64(const f16* g, long K, f16* l, int h, int t) {
  int rr = t >> 3, sp = t & 7;
  int row = h * 64 + rr;
  int sl = sp ^ (rr & 7);
  gl_lds16(g + (long)row * K + (sl << 3), (char*)l + ((row << 6) + (sp << 3)) * 2);
}

__device__ __forceinline__ void read_a(f16x8 (&d)[4][2], const f16* base, int q,
                                       int wm, int l15, int l4) {
#pragma unroll
  for (int mf = 0; mf < 4; ++mf)
#pragma unroll
    for (int kk = 0; kk < 2; ++kk) {
      int row = wm * 128 + (q * 4 + mf) * 16 + l15;
      int sl = kk * 4 + l4;
      d[mf][kk] = *(const f16x8*)(base + row * 64 + ((sl ^ (row & 7)) << 3));
    }
}

__device__ __forceinline__ void read_b1(f16x8 (&d)[2], const f16* base, int f,
                                        int wn, int l15, int l4) {
#pragma unroll
  for (int kk = 0; kk < 2; ++kk) {
    int row = wn * 32 + f * 16 + l15;
    int sl = kk * 4 + l4;
    d[kk] = *(const f16x8*)(base + row * 64 + ((sl ^ (row & 7)) << 3));
  }
}

__device__ __forceinline__ void mfma_n(f32x4 (&acc)[8][2], const f16x8 (&Af)[4][2],
                                       const f16x8 (&Bf)[2], int q, int f) {
#pragma unroll
  for (int mf = 0; mf < 4; ++mf)
#pragma unroll
    for (int kk = 0; kk < 2; ++kk)
      acc[q * 4 + mf][f] = __builtin_amdgcn_mfma_f32_16x16x32_f16(
          Af[mf][kk], Bf[kk], acc[q * 4 + mf][f], 0, 0, 0);
}

__device__ __forceinline__ void n128_core(f32x4 (&acc)[8][2], const f16* Ag,
                                          const f16* Bg, long L, int NT,
                                          f16* lds, int tid, int wm, int wn,
                                          int l15, int l4) {
  f16* As0 = lds;
  f16* As1 = lds + 16384;
  f16* Bs0 = lds + 32768;
  f16* Bs1 = lds + 40960;
  f16x8 a[4][2], b[2], b2[2];
  const int NIT = NT >> 1;

  stage64(Bg, L, Bs0, 0, tid); stage64(Bg, L, Bs0, 1, tid);
#pragma unroll
  for (int h = 0; h < 4; ++h) stage64(Ag, L, As0, h, tid);
  stage64(Bg + 64, L, Bs1, 0, tid); stage64(Bg + 64, L, Bs1, 1, tid);
#pragma unroll
  for (int h = 0; h < 4; ++h) stage64(Ag + 64, L, As1, h, tid);
  WAITV6();
  BAR();

  for (int i = 0; i < NIT; ++i) {
    int t2 = 2 * i + 2, t3 = 2 * i + 3;
    long k2 = (long)((t2 < NT) ? t2 : NT - 1) << 6;
    long k3 = (long)((t3 < NT) ? t3 : NT - 1) << 6;
    read_a(a, As0, 0, wm, l15, l4);
    read_b1(b, Bs0, 0, wn, l15, l4);
    BAR(); PRIO1(); mfma_n(acc, a, b, 0, 0); PRIO0(); BAR();
    read_b1(b2, Bs0, 1, wn, l15, l4);
    BAR(); PRIO1(); mfma_n(acc, a, b2, 0, 1); PRIO0(); BAR();
    read_a(a, As0, 1, wm, l15, l4);
    stage64(Bg + k2, L, Bs0, 0, tid); stage64(Bg + k2, L, Bs0, 1, tid);
    BAR(); PRIO1(); mfma_n(acc, a, b2, 1, 1); PRIO0(); BAR();
#pragma unroll
    for (int h = 0; h < 4; ++h) stage64(Ag + k2, L, As0, h, tid);
    BAR(); PRIO1(); mfma_n(acc, a, b, 1, 0); PRIO0();
    WAITV6();
    BAR();
    read_a(a, As1, 0, wm, l15, l4);
    read_b1(b, Bs1, 0, wn, l15, l4);
    BAR(); PRIO1(); mfma_n(acc, a, b, 0, 0); PRIO0(); BAR();
    read_b1(b2, Bs1, 1, wn, l15, l4);
    BAR(); PRIO1(); mfma_n(acc, a, b2, 0, 1); PRIO0(); BAR();
    read_a(a, As1, 1, wm, l15, l4);
    stage64(Bg + k3, L, Bs1, 0, tid); stage64(Bg + k3, L, Bs1, 1, tid);
    BAR(); PRIO1(); mfma_n(acc, a, b2, 1, 1); PRIO0(); BAR();
#pragma unroll
    for (int h = 0; h < 4; ++h) stage64(Ag + k3, L, As1, h, tid);
    BAR(); PRIO1(); mfma_n(acc, a, b, 1, 0); PRIO0();
    WAITV6();
    BAR();
  }
  WAITV0();
}

// ---------- uber: persistent QK+WV+PV over XCD-aligned item list ----------
// kind 0: P'=(col<count)?exp(acc/32):0, rowsum atomic, doneQK inc (release).
// kind 1: VWt f16 store, doneWV inc (release).
// kind 2: spin on doneQK[bz][by] & doneWV[bz][bx>>1] (acquire), out f32 store.
__global__ __launch_bounds__(512, 1) void uber(const f16* __restrict__ Qh,
                                               const f16* __restrict__ Kc,
                                               const f16* __restrict__ Vc,
                                               const f16* __restrict__ Wh,
                                               f16* __restrict__ P,
                                               f16* __restrict__ VWt,
                                               float* __restrict__ out,
                                               const float* __restrict__ bias,
                                               float* __restrict__ rowsum,
                                               const int2* __restrict__ cnt,
                                               const int* __restrict__ items,
                                               const int* __restrict__ nit,
                                               int* __restrict__ done) {
  extern __shared__ f16 lds[];
  const int tid = threadIdx.x;
  const int lane = tid & 63, wv = tid >> 6;
  const int wm = wv >> 2, wn = wv & 3;
  const int l15 = lane & 15, l4 = lane >> 4;
  const int n = nit[0];
  int* doneQK = done;       // [4][8]
  int* doneWV = done + 32;  // [4][4]

  for (int idx = blockIdx.x; idx < n; idx += 256) {
    const int it = items[idx];
    const int kind = (it >> 24) & 3;
    if (kind == 3) continue;
    const int bx = it & 255, by = (it >> 8) & 255, bz = (it >> 16) & 255;
    const int2 cc = cnt[bz];
    const long m0 = (long)by * 256;
    const long n0 = (long)bx * 128;
    const f16* Ag;
    const f16* Bg;
    long L;
    int NT;
    if (kind == 0) {
      Ag = Qh + (long)bz * SS * EE + m0 * EE; Bg = Kc + (long)bz * SS * EE + n0 * EE;
      L = EE; NT = EE >> 6;
    } else if (kind == 1) {
      Ag = Wh + m0 * EE; Bg = Vc + (long)bz * SS * EE + n0 * EE;
      L = EE; NT = EE >> 6;
    } else {
      const int need = cc.y >> 7;
      if (tid == 0) {
        while (__hip_atomic_load(&doneQK[bz * 8 + by], __ATOMIC_RELAXED,
                                 __HIP_MEMORY_SCOPE_AGENT) < need)
          __builtin_amdgcn_s_sleep(8);
        while (__hip_atomic_load(&doneWV[bz * 4 + (bx >> 1)], __ATOMIC_RELAXED,
                                 __HIP_MEMORY_SCOPE_AGENT) < need)
          __builtin_amdgcn_s_sleep(8);
      }
      BAR();
      __threadfence();  // acquire: fresh P/VWt/rowsum across XCDs
      Ag = P + (long)bz * SS * SS + m0 * SS; Bg = VWt + (long)bz * EE * SS + n0 * SS;
      L = SS; NT = cc.y >> 6;
    }

    f32x4 acc[8][2] = {};
    n128_core(acc, Ag, Bg, L, NT, lds, tid, wm, wn, l15, l4);

    const long crow = m0 + wm * 128 + l4 * 4;
    const long ccol = n0 + wn * 32 + l15;
    if (kind == 0) {
      const int count = cc.x;
      f16* Co = P + (long)bz * SS * SS;
      float* rs = rowsum + (bz << 11);
      const float scale = 1.0f / 32.0f;
      int mv[2];
#pragma unroll
      for (int nf = 0; nf < 2; ++nf) mv[nf] = (ccol + nf * 16) < count;
#pragma unroll
      for (int mf = 0; mf < 8; ++mf)
#pragma unroll
        for (int jj = 0; jj < 4; ++jj) {
          float rp = 0.f;
#pragma unroll
          for (int nf = 0; nf < 2; ++nf) {
            float p = mv[nf] ? __expf(acc[mf][nf][jj] * scale) : 0.f;
            Co[(crow + mf * 16 + jj) * SS + ccol + nf * 16] = (f16)p;
            rp += p;
          }
          rp += __shfl_xor(rp, 1); rp += __shfl_xor(rp, 2);
          rp += __shfl_xor(rp, 4); rp += __shfl_xor(rp, 8);
          if (l15 == 0) atomicAdd(&rs[crow + mf * 16 + jj], rp);
        }
      __threadfence();  // release P + rowsum
      BAR();
      if (tid == 0) atomicAdd(&doneQK[bz * 8 + by], 1);
    } else if (kind == 1) {
      f16* Co = VWt + (long)bz * EE * SS;
#pragma unroll
      for (int mf = 0; mf < 8; ++mf)
#pragma unroll
        for (int nf = 0; nf < 2; ++nf)
#pragma unroll
          for (int jj = 0; jj < 4; ++jj)
            Co[(crow + mf * 16 + jj) * SS + ccol + nf * 16] = (f16)acc[mf][nf][jj];
      __threadfence();  // release VWt
      BAR();
      if (tid == 0) atomicAdd(&doneWV[bz * 4 + by], 1);
    } else {
      float* Co = out + (long)bz * SS * EE;
      const float* rs = rowsum + (bz << 11);
      float bv[2];
#pragma unroll
      for (int nf = 0; nf < 2; ++nf) bv[nf] = bias[ccol + nf * 16];
#pragma unroll
      for (int mf = 0; mf < 8; ++mf)
#pragma unroll
        for (int jj = 0; jj < 4; ++jj) {
          float inv = 1.f / rs[crow + mf * 16 + jj];
#pragma unroll
          for (int nf = 0; nf < 2; ++nf)
            Co[(crow + mf * 16 + jj) * EE + ccol + nf * 16] =
                acc[mf][nf][jj] * inv + bv[nf];
        }
    }
  }
}

extern "C" void kernel_launch(void* const* d_in, const int* in_sizes, int n_in,
                              void* d_out, int out_size, void* d_ws, size_t ws_size,
                              hipStream_t stream) {
  const float* V = (const float*)d_in[0];
  const float* Kin = (const float*)d_in[1];
  const float* Q = (const float*)d_in[2];
  const int* mask = (const int*)d_in[3];
  const float* W = (const float*)d_in[4];
  const float* bias = (const float*)d_in[5];
  float* out = (float*)d_out;

  const long NE = (long)BB * SS * EE;  // 8388608
  f16* Qh = (f16*)d_ws;                  // NE
  f16* Kc = Qh + NE;                     // NE
  f16* Vc = Kc + NE;                     // NE
  f16* Wh = Vc + NE;                     // EE*EE
  f16* VWt = Wh + (long)EE * EE;         // NE ([B][E][S] stride SS)
  f16* P = VWt + NE;                     // 2*NE ([B][S][S] stride SS)
  float* rowsum = (float*)(P + (long)BB * SS * SS);  // B*S
  int* pos = (int*)(rowsum + (long)BB * SS);         // B*S
  int2* cnt = (int2*)(pos + (long)BB * SS);          // B
  int* items = (int*)(cnt + BB);                     // <=1024
  int* nit = items + 1024;                           // 1
  int* done = nit + 1;                               // 48 (32 QK + 16 WV)

  const size_t LDS_N = 98304;
  hipFuncSetAttribute((const void*)uber, hipFuncAttributeMaxDynamicSharedMemorySize, LDS_N);

  prep<<<BB, 256, 0, stream>>>(mask, pos, cnt, Kc, Vc);
  prep2<<<4610 + BB * SS, 256, 0, stream>>>(Q, W, Kin, V, mask, pos, cnt,
                                            Qh, Wh, Kc, Vc, rowsum, items, nit, done);
  uber<<<256, 512, LDS_N, stream>>>(Qh, Kc, Vc, Wh, P, VWt, out, bias, rowsum,
                                    cnt, items, nit, done);
}

// Round 8
// 102.611 us; speedup vs baseline: 2.5689x; 2.5689x over previous
//
#include <hip/hip_runtime.h>

#define BB 4
#define SS 2048
#define EE 1024

typedef _Float16 f16;
typedef _Float16 f16x4 __attribute__((ext_vector_type(4)));
typedef _Float16 f16x8 __attribute__((ext_vector_type(8)));
typedef float f32x4 __attribute__((ext_vector_type(4)));

typedef const __attribute__((address_space(1))) void* gas_ptr;
typedef __attribute__((address_space(3))) void* las_ptr;

__device__ __forceinline__ void gl_lds16(const void* g, void* l) {
  __builtin_amdgcn_global_load_lds((gas_ptr)g, (las_ptr)l, 16, 0, 0);
}

#define BAR() __builtin_amdgcn_s_barrier()
#define PRIO1() __builtin_amdgcn_s_setprio(1)
#define PRIO0() __builtin_amdgcn_s_setprio(0)
#define WAITV6() asm volatile("s_waitcnt vmcnt(6)" ::: "memory")
#define WAITV0() asm volatile("s_waitcnt vmcnt(0)" ::: "memory")

// ---------- prep: per-batch mask prefix-scan + pad-row zeroing ----------
__global__ __launch_bounds__(256) void prep(const int* __restrict__ mask,
                                            int* __restrict__ pos,
                                            int2* __restrict__ cnt,
                                            f16* __restrict__ Kc,
                                            f16* __restrict__ Vc) {
  const int b = blockIdx.x, t = threadIdx.x;
  const int* mb = mask + b * SS;
  int4 a0 = ((const int4*)mb)[t * 2];
  int4 a1 = ((const int4*)mb)[t * 2 + 1];
  int m[8] = {a0.x, a0.y, a0.z, a0.w, a1.x, a1.y, a1.z, a1.w};
  int tot = 0;
#pragma unroll
  for (int j = 0; j < 8; ++j) tot += m[j];
  __shared__ int sc[256];
  sc[t] = tot;
  __syncthreads();
  for (int off = 1; off < 256; off <<= 1) {
    int v = (t >= off) ? sc[t - off] : 0;
    __syncthreads();
    sc[t] += v;
    __syncthreads();
  }
  const int count = sc[255];
  const int padded = (count + 127) & ~127;
  int run = sc[t] - tot;  // exclusive prefix
#pragma unroll
  for (int j = 0; j < 8; ++j) {
    pos[b * SS + t * 8 + j] = run;
    run += m[j];
  }
  if (t == 0) cnt[b] = make_int2(count, padded);
  const int nz = (padded - count) * 128;
  f16x8 z = {};
  for (int i = t; i < nz; i += 256) {
    int r = count + (i >> 7), cc = i & 127;
    ((f16x8*)(Kc + ((long)b * SS + r) * EE))[cc] = z;
    ((f16x8*)(Vc + ((long)b * SS + r) * EE))[cc] = z;
  }
}

// ---------- prep2: Q/W cvt, rowsum zero, XCD-local item-list build, gather ----------
__global__ __launch_bounds__(256) void prep2(const float* __restrict__ Q,
                                             const float* __restrict__ W,
                                             const float* __restrict__ K,
                                             const float* __restrict__ V,
                                             const int* __restrict__ mask,
                                             const int* __restrict__ pos,
                                             const int2* __restrict__ cnt,
                                             f16* __restrict__ Qh,
                                             f16* __restrict__ Wh,
                                             f16* __restrict__ Kc,
                                             f16* __restrict__ Vc,
                                             float* __restrict__ rowsum,
                                             int* __restrict__ items,
                                             int* __restrict__ nit) {
  const int x = blockIdx.x, t = threadIdx.x;
  if (x < 4608) {  // Q cvt (x<4096) or W cvt
    const float* in = (x < 4096) ? Q : W;
    f16* out = (x < 4096) ? Qh : Wh;
    long i = (long)(x < 4096 ? x : x - 4096) * 256 + t;
    float4 v0 = ((const float4*)in)[i * 2];
    float4 v1 = ((const float4*)in)[i * 2 + 1];
    f16x8 o;
    o[0] = (f16)v0.x; o[1] = (f16)v0.y; o[2] = (f16)v0.z; o[3] = (f16)v0.w;
    o[4] = (f16)v1.x; o[5] = (f16)v1.y; o[6] = (f16)v1.z; o[7] = (f16)v1.w;
    ((f16x8*)out)[i] = o;
    return;
  }
  if (x == 4608) {  // zero rowsum[B*S]
    float4 z = {0.f, 0.f, 0.f, 0.f};
#pragma unroll
    for (int r = 0; r < 8; ++r) ((float4*)rowsum)[t + r * 256] = z;
    return;
  }
  if (x == 4609) {  // build item list: XCD x owns bz=x>>1, half (x&1) of M-panels
    if (t < 8) {
      int nbx[4];
#pragma unroll
      for (int zz = 0; zz < 4; ++zz) nbx[zz] = cnt[zz].y >> 7;
      int mxn = nbx[0];
#pragma unroll
      for (int zz = 1; zz < 4; ++zz) mxn = nbx[zz] > mxn ? nbx[zz] : mxn;
      const int mx = 6 * mxn;  // 4*nbx QK + 2*nbx WV, padded to common length
      const int bz = t >> 1, half = t & 1;
      int g = 0;
      // QK: 4 M-panels of this half, all column-blocks (Kc panel L2-resident)
      for (int q = 0; q < 4; ++q)
        for (int bx = 0; bx < nbx[bz]; ++bx)
          items[(g++ << 3) | t] = bx | ((half * 4 + q) << 8) | (bz << 16);
      // WV: 2 E-panels of this half
      for (int q = 0; q < 2; ++q)
        for (int bx = 0; bx < nbx[bz]; ++bx)
          items[(g++ << 3) | t] = bx | ((half * 2 + q) << 8) | (bz << 16) | (1 << 24);
      for (; g < mx; ++g) items[(g << 3) | t] = (3 << 24);  // skip pad
      if (t == 0) nit[0] = mx << 3;
    }
    return;
  }
  // gather: masked K/V rows -> compacted f16
  const int r = x - 4610, b = r >> 11, s = r & (SS - 1);
  if (!mask[b * SS + s]) return;
  const int p = pos[b * SS + s];
  float4 kv = ((const float4*)(K + ((long)b * SS + s) * EE))[t];
  float4 vv = ((const float4*)(V + ((long)b * SS + s) * EE))[t];
  f16x4 ko, vo;
  ko[0] = (f16)kv.x; ko[1] = (f16)kv.y; ko[2] = (f16)kv.z; ko[3] = (f16)kv.w;
  vo[0] = (f16)vv.x; vo[1] = (f16)vv.y; vo[2] = (f16)vv.z; vo[3] = (f16)vv.w;
  ((f16x4*)(Kc + ((long)b * SS + p) * EE))[t] = ko;
  ((f16x4*)(Vc + ((long)b * SS + p) * EE))[t] = vo;
}

// ---------- shared 256x128 8-phase GEMM core (R6-verified, unchanged) ----------
__device__ __forceinline__ void stage64(const f16* g, long K, f16* l, int h, int t) {
  int rr = t >> 3, sp = t & 7;
  int row = h * 64 + rr;
  int sl = sp ^ (rr & 7);
  gl_lds16(g + (long)row * K + (sl << 3), (char*)l + ((row << 6) + (sp << 3)) * 2);
}

__device__ __forceinline__ void read_a(f16x8 (&d)[4][2], const f16* base, int q,
                                       int wm, int l15, int l4) {
#pragma unroll
  for (int mf = 0; mf < 4; ++mf)
#pragma unroll
    for (int kk = 0; kk < 2; ++kk) {
      int row = wm * 128 + (q * 4 + mf) * 16 + l15;
      int sl = kk * 4 + l4;
      d[mf][kk] = *(const f16x8*)(base + row * 64 + ((sl ^ (row & 7)) << 3));
    }
}

__device__ __forceinline__ void read_b1(f16x8 (&d)[2], const f16* base, int f,
                                        int wn, int l15, int l4) {
#pragma unroll
  for (int kk = 0; kk < 2; ++kk) {
    int row = wn * 32 + f * 16 + l15;
    int sl = kk * 4 + l4;
    d[kk] = *(const f16x8*)(base + row * 64 + ((sl ^ (row & 7)) << 3));
  }
}

__device__ __forceinline__ void mfma_n(f32x4 (&acc)[8][2], const f16x8 (&Af)[4][2],
                                       const f16x8 (&Bf)[2], int q, int f) {
#pragma unroll
  for (int mf = 0; mf < 4; ++mf)
#pragma unroll
    for (int kk = 0; kk < 2; ++kk)
      acc[q * 4 + mf][f] = __builtin_amdgcn_mfma_f32_16x16x32_f16(
          Af[mf][kk], Bf[kk], acc[q * 4 + mf][f], 0, 0, 0);
}

__device__ __forceinline__ void n128_core(f32x4 (&acc)[8][2], const f16* Ag,
                                          const f16* Bg, long L, int NT,
                                          f16* lds, int tid, int wm, int wn,
                                          int l15, int l4) {
  f16* As0 = lds;
  f16* As1 = lds + 16384;
  f16* Bs0 = lds + 32768;
  f16* Bs1 = lds + 40960;
  f16x8 a[4][2], b[2], b2[2];
  const int NIT = NT >> 1;

  stage64(Bg, L, Bs0, 0, tid); stage64(Bg, L, Bs0, 1, tid);
#pragma unroll
  for (int h = 0; h < 4; ++h) stage64(Ag, L, As0, h, tid);
  stage64(Bg + 64, L, Bs1, 0, tid); stage64(Bg + 64, L, Bs1, 1, tid);
#pragma unroll
  for (int h = 0; h < 4; ++h) stage64(Ag + 64, L, As1, h, tid);
  WAITV6();
  BAR();

  for (int i = 0; i < NIT; ++i) {
    int t2 = 2 * i + 2, t3 = 2 * i + 3;
    long k2 = (long)((t2 < NT) ? t2 : NT - 1) << 6;
    long k3 = (long)((t3 < NT) ? t3 : NT - 1) << 6;
    read_a(a, As0, 0, wm, l15, l4);
    read_b1(b, Bs0, 0, wn, l15, l4);
    BAR(); PRIO1(); mfma_n(acc, a, b, 0, 0); PRIO0(); BAR();
    read_b1(b2, Bs0, 1, wn, l15, l4);
    BAR(); PRIO1(); mfma_n(acc, a, b2, 0, 1); PRIO0(); BAR();
    read_a(a, As0, 1, wm, l15, l4);
    stage64(Bg + k2, L, Bs0, 0, tid); stage64(Bg + k2, L, Bs0, 1, tid);
    BAR(); PRIO1(); mfma_n(acc, a, b2, 1, 1); PRIO0(); BAR();
#pragma unroll
    for (int h = 0; h < 4; ++h) stage64(Ag + k2, L, As0, h, tid);
    BAR(); PRIO1(); mfma_n(acc, a, b, 1, 0); PRIO0();
    WAITV6();
    BAR();
    read_a(a, As1, 0, wm, l15, l4);
    read_b1(b, Bs1, 0, wn, l15, l4);
    BAR(); PRIO1(); mfma_n(acc, a, b, 0, 0); PRIO0(); BAR();
    read_b1(b2, Bs1, 1, wn, l15, l4);
    BAR(); PRIO1(); mfma_n(acc, a, b2, 0, 1); PRIO0(); BAR();
    read_a(a, As1, 1, wm, l15, l4);
    stage64(Bg + k3, L, Bs1, 0, tid); stage64(Bg + k3, L, Bs1, 1, tid);
    BAR(); PRIO1(); mfma_n(acc, a, b2, 1, 1); PRIO0(); BAR();
#pragma unroll
    for (int h = 0; h < 4; ++h) stage64(Ag + k3, L, As1, h, tid);
    BAR(); PRIO1(); mfma_n(acc, a, b, 1, 0); PRIO0();
    WAITV6();
    BAR();
  }
  WAITV0();
}

// ---------- uber: persistent QK+WV over XCD-local item list (no deps) ----------
__global__ __launch_bounds__(512, 1) void uber(const f16* __restrict__ Qh,
                                               const f16* __restrict__ Kc,
                                               const f16* __restrict__ Vc,
                                               const f16* __restrict__ Wh,
                                               f16* __restrict__ P,
                                               f16* __restrict__ VWt,
                                               float* __restrict__ rowsum,
                                               const int2* __restrict__ cnt,
                                               const int* __restrict__ items,
                                               const int* __restrict__ nit) {
  extern __shared__ f16 lds[];
  const int tid = threadIdx.x;
  const int lane = tid & 63, wv = tid >> 6;
  const int wm = wv >> 2, wn = wv & 3;
  const int l15 = lane & 15, l4 = lane >> 4;
  const int n = nit[0];

  for (int idx = blockIdx.x; idx < n; idx += 256) {
    const int it = items[idx];
    const int kind = (it >> 24) & 3;
    if (kind == 3) continue;
    const int bx = it & 255, by = (it >> 8) & 255, bz = (it >> 16) & 255;
    const long m0 = (long)by * 256;
    const long n0 = (long)bx * 128;
    const f16* Ag = kind ? (Wh + m0 * EE) : (Qh + (long)bz * SS * EE + m0 * EE);
    const f16* Bg = (kind ? Vc : Kc) + (long)bz * SS * EE + n0 * EE;

    f32x4 acc[8][2] = {};
    n128_core(acc, Ag, Bg, EE, EE >> 6, lds, tid, wm, wn, l15, l4);

    const long crow = m0 + wm * 128 + l4 * 4;
    const long ccol = n0 + wn * 32 + l15;
    if (kind == 0) {
      const int count = cnt[bz].x;
      f16* Co = P + (long)bz * SS * SS;
      float* rs = rowsum + (bz << 11);
      const float scale = 1.0f / 32.0f;
      int mv[2];
#pragma unroll
      for (int nf = 0; nf < 2; ++nf) mv[nf] = (ccol + nf * 16) < count;
#pragma unroll
      for (int mf = 0; mf < 8; ++mf)
#pragma unroll
        for (int jj = 0; jj < 4; ++jj) {
          float rp = 0.f;
#pragma unroll
          for (int nf = 0; nf < 2; ++nf) {
            float p = mv[nf] ? __expf(acc[mf][nf][jj] * scale) : 0.f;
            Co[(crow + mf * 16 + jj) * SS + ccol + nf * 16] = (f16)p;
            rp += p;
          }
          rp += __shfl_xor(rp, 1); rp += __shfl_xor(rp, 2);
          rp += __shfl_xor(rp, 4); rp += __shfl_xor(rp, 8);
          if (l15 == 0) atomicAdd(&rs[crow + mf * 16 + jj], rp);
        }
    } else {
      f16* Co = VWt + (long)bz * EE * SS;
#pragma unroll
      for (int mf = 0; mf < 8; ++mf)
#pragma unroll
        for (int nf = 0; nf < 2; ++nf)
#pragma unroll
          for (int jj = 0; jj < 4; ++jj)
            Co[(crow + mf * 16 + jj) * SS + ccol + nf * 16] = (f16)acc[mf][nf][jj];
    }
  }
}

// ---------- PV: out = (P' @ VWt^T) / rowsum + bias (f32) ----------
// Analytic XCD-local decode: XCD x = d&7 owns bz = x>>1, by-half = x&1.
__global__ __launch_bounds__(512, 1) void pv128(const f16* __restrict__ P,
                                                const f16* __restrict__ VWt,
                                                float* __restrict__ out,
                                                const float* __restrict__ bias,
                                                const float* __restrict__ rowsum,
                                                const int2* __restrict__ cnt) {
  extern __shared__ f16 lds[];
  const int d = blockIdx.x;  // 256 linear
  const int x = d & 7, r = d >> 3;
  const int bz = x >> 1;
  const int by = (x & 1) * 4 + (r & 3);
  const int bx = r >> 2;  // E-panel 0..7
  int2 cc = cnt[bz];
  const int padded = cc.y;
  if (padded <= 0) return;  // never taken; forces cnt-load wait before staging
  const long m0 = (long)by * 256;
  const long n0 = (long)bx * 128;
  const int tid = threadIdx.x;
  const int lane = tid & 63, wv = tid >> 6;
  const int wm = wv >> 2, wn = wv & 3;
  const int l15 = lane & 15, l4 = lane >> 4;
  const f16* Ag = P + (long)bz * SS * SS + m0 * SS;
  const f16* Bg = VWt + (long)bz * EE * SS + n0 * SS;

  f32x4 acc[8][2] = {};
  n128_core(acc, Ag, Bg, SS, padded >> 6, lds, tid, wm, wn, l15, l4);

  const long crow = m0 + wm * 128 + l4 * 4;
  const long ccol = n0 + wn * 32 + l15;
  float* Co = out + (long)bz * SS * EE;
  const float* rs = rowsum + (bz << 11);
  float bv[2];
#pragma unroll
  for (int nf = 0; nf < 2; ++nf) bv[nf] = bias[ccol + nf * 16];
#pragma unroll
  for (int mf = 0; mf < 8; ++mf)
#pragma unroll
    for (int jj = 0; jj < 4; ++jj) {
      float inv = 1.f / rs[crow + mf * 16 + jj];
#pragma unroll
      for (int nf = 0; nf < 2; ++nf)
        Co[(crow + mf * 16 + jj) * EE + ccol + nf * 16] =
            acc[mf][nf][jj] * inv + bv[nf];
    }
}

extern "C" void kernel_launch(void* const* d_in, const int* in_sizes, int n_in,
                              void* d_out, int out_size, void* d_ws, size_t ws_size,
                              hipStream_t stream) {
  const float* V = (const float*)d_in[0];
  const float* Kin = (const float*)d_in[1];
  const float* Q = (const float*)d_in[2];
  const int* mask = (const int*)d_in[3];
  const float* W = (const float*)d_in[4];
  const float* bias = (const float*)d_in[5];
  float* out = (float*)d_out;

  const long NE = (long)BB * SS * EE;  // 8388608
  f16* Qh = (f16*)d_ws;                  // NE
  f16* Kc = Qh + NE;                     // NE
  f16* Vc = Kc + NE;                     // NE
  f16* Wh = Vc + NE;                     // EE*EE
  f16* VWt = Wh + (long)EE * EE;         // NE ([B][E][S] stride SS)
  f16* P = VWt + NE;                     // 2*NE ([B][S][S] stride SS)
  float* rowsum = (float*)(P + (long)BB * SS * SS);  // B*S
  int* pos = (int*)(rowsum + (long)BB * SS);         // B*S
  int2* cnt = (int2*)(pos + (long)BB * SS);          // B
  int* items = (int*)(cnt + BB);                     // <=1024
  int* nit = items + 1024;                           // 1

  const size_t LDS_N = 98304;
  hipFuncSetAttribute((const void*)uber, hipFuncAttributeMaxDynamicSharedMemorySize, LDS_N);
  hipFuncSetAttribute((const void*)pv128, hipFuncAttributeMaxDynamicSharedMemorySize, LDS_N);

  prep<<<BB, 256, 0, stream>>>(mask, pos, cnt, Kc, Vc);
  prep2<<<4610 + BB * SS, 256, 0, stream>>>(Q, W, Kin, V, mask, pos, cnt,
                                            Qh, Wh, Kc, Vc, rowsum, items, nit);
  uber<<<256, 512, LDS_N, stream>>>(Qh, Kc, Vc, Wh, P, VWt, rowsum, cnt, items, nit);
  pv128<<<256, 512, LDS_N, stream>>>(P, VWt, out, bias, rowsum, cnt);
}

// Round 9
// 97.588 us; speedup vs baseline: 2.7011x; 1.0515x over previous
//
#include <hip/hip_runtime.h>

#define BB 4
#define SS 2048
#define EE 1024

typedef _Float16 f16;
typedef _Float16 f16x4 __attribute__((ext_vector_type(4)));
typedef _Float16 f16x8 __attribute__((ext_vector_type(8)));
typedef float f32x4 __attribute__((ext_vector_type(4)));

typedef const __attribute__((address_space(1))) void* gas_ptr;
typedef __attribute__((address_space(3))) void* las_ptr;

__device__ __forceinline__ void gl_lds16(const void* g, void* l) {
  __builtin_amdgcn_global_load_lds((gas_ptr)g, (las_ptr)l, 16, 0, 0);
}

#define BAR() __builtin_amdgcn_s_barrier()
#define PRIO1() __builtin_amdgcn_s_setprio(1)
#define PRIO0() __builtin_amdgcn_s_setprio(0)
#define WAITV8() asm volatile("s_waitcnt vmcnt(8)" ::: "memory")
#define WAITV6() asm volatile("s_waitcnt vmcnt(6)" ::: "memory")
#define WAITV4() asm volatile("s_waitcnt vmcnt(4)" ::: "memory")
#define WAITV0() asm volatile("s_waitcnt vmcnt(0)" ::: "memory")

// ---------- prep: per-batch mask prefix-scan + pad-row zeroing (256-granular) ----------
__global__ __launch_bounds__(256) void prep(const int* __restrict__ mask,
                                            int* __restrict__ pos,
                                            int2* __restrict__ cnt,
                                            f16* __restrict__ Kc,
                                            f16* __restrict__ Vc) {
  const int b = blockIdx.x, t = threadIdx.x;
  const int* mb = mask + b * SS;
  int4 a0 = ((const int4*)mb)[t * 2];
  int4 a1 = ((const int4*)mb)[t * 2 + 1];
  int m[8] = {a0.x, a0.y, a0.z, a0.w, a1.x, a1.y, a1.z, a1.w};
  int tot = 0;
#pragma unroll
  for (int j = 0; j < 8; ++j) tot += m[j];
  __shared__ int sc[256];
  sc[t] = tot;
  __syncthreads();
  for (int off = 1; off < 256; off <<= 1) {
    int v = (t >= off) ? sc[t - off] : 0;
    __syncthreads();
    sc[t] += v;
    __syncthreads();
  }
  const int count = sc[255];
  const int padded = (count + 255) & ~255;  // 256-granular for the 256^2 core
  int run = sc[t] - tot;  // exclusive prefix
#pragma unroll
  for (int j = 0; j < 8; ++j) {
    pos[b * SS + t * 8 + j] = run;
    run += m[j];
  }
  if (t == 0) cnt[b] = make_int2(count, padded);
  const int nz = (padded - count) * 128;
  f16x8 z = {};
  for (int i = t; i < nz; i += 256) {
    int r = count + (i >> 7), cc = i & 127;
    ((f16x8*)(Kc + ((long)b * SS + r) * EE))[cc] = z;
    ((f16x8*)(Vc + ((long)b * SS + r) * EE))[cc] = z;
  }
}

// ---------- prep2: Q/W cvt, rowsum zero, XCD-local item-list build, gather ----------
__global__ __launch_bounds__(256) void prep2(const float* __restrict__ Q,
                                             const float* __restrict__ W,
                                             const float* __restrict__ K,
                                             const float* __restrict__ V,
                                             const int* __restrict__ mask,
                                             const int* __restrict__ pos,
                                             const int2* __restrict__ cnt,
                                             f16* __restrict__ Qh,
                                             f16* __restrict__ Wh,
                                             f16* __restrict__ Kc,
                                             f16* __restrict__ Vc,
                                             float* __restrict__ rowsum,
                                             int* __restrict__ items,
                                             int* __restrict__ nit) {
  const int x = blockIdx.x, t = threadIdx.x;
  if (x < 4608) {  // Q cvt (x<4096) or W cvt
    const float* in = (x < 4096) ? Q : W;
    f16* out = (x < 4096) ? Qh : Wh;
    long i = (long)(x < 4096 ? x : x - 4096) * 256 + t;
    float4 v0 = ((const float4*)in)[i * 2];
    float4 v1 = ((const float4*)in)[i * 2 + 1];
    f16x8 o;
    o[0] = (f16)v0.x; o[1] = (f16)v0.y; o[2] = (f16)v0.z; o[3] = (f16)v0.w;
    o[4] = (f16)v1.x; o[5] = (f16)v1.y; o[6] = (f16)v1.z; o[7] = (f16)v1.w;
    ((f16x8*)out)[i] = o;
    return;
  }
  if (x == 4608) {  // zero rowsum[B*S]
    float4 z = {0.f, 0.f, 0.f, 0.f};
#pragma unroll
    for (int r = 0; r < 8; ++r) ((float4*)rowsum)[t + r * 256] = z;
    return;
  }
  if (x == 4609) {  // item list (256^2 items): XCD x owns bz=x>>1, half (x&1)
    if (t < 8) {
      int nbx[4];
#pragma unroll
      for (int zz = 0; zz < 4; ++zz) nbx[zz] = cnt[zz].y >> 8;  // 256-col blocks
      int mxn = nbx[0];
#pragma unroll
      for (int zz = 1; zz < 4; ++zz) mxn = nbx[zz] > mxn ? nbx[zz] : mxn;
      const int mx = 6 * mxn;  // 4*nbx QK + 2*nbx WV, padded to common length
      const int bz = t >> 1, half = t & 1;
      int g = 0;
      // QK: 4 of 8 S-panels (this half), all 256-col blocks (Kc panel L2-resident)
      for (int q = 0; q < 4; ++q)
        for (int bx = 0; bx < nbx[bz]; ++bx)
          items[(g++ << 3) | t] = bx | ((half * 4 + q) << 8) | (bz << 16);
      // WV: 2 of 4 E-panels (this half)
      for (int q = 0; q < 2; ++q)
        for (int bx = 0; bx < nbx[bz]; ++bx)
          items[(g++ << 3) | t] = bx | ((half * 2 + q) << 8) | (bz << 16) | (1 << 24);
      for (; g < mx; ++g) items[(g << 3) | t] = (3 << 24);  // skip pad
      if (t == 0) nit[0] = mx << 3;
    }
    return;
  }
  // gather: masked K/V rows -> compacted f16
  const int r = x - 4610, b = r >> 11, s = r & (SS - 1);
  if (!mask[b * SS + s]) return;
  const int p = pos[b * SS + s];
  float4 kv = ((const float4*)(K + ((long)b * SS + s) * EE))[t];
  float4 vv = ((const float4*)(V + ((long)b * SS + s) * EE))[t];
  f16x4 ko, vo;
  ko[0] = (f16)kv.x; ko[1] = (f16)kv.y; ko[2] = (f16)kv.z; ko[3] = (f16)kv.w;
  vo[0] = (f16)vv.x; vo[1] = (f16)vv.y; vo[2] = (f16)vv.z; vo[3] = (f16)vv.w;
  ((f16x4*)(Kc + ((long)b * SS + p) * EE))[t] = ko;
  ((f16x4*)(Vc + ((long)b * SS + p) * EE))[t] = vo;
}

// ---------- shared staging / read helpers (swizzle: slot ^= row&7) ----------
__device__ __forceinline__ void stage64(const f16* g, long K, f16* l, int h, int t) {
  int rr = t >> 3, sp = t & 7;
  int row = h * 64 + rr;
  int sl = sp ^ (rr & 7);
  gl_lds16(g + (long)row * K + (sl << 3), (char*)l + ((row << 6) + (sp << 3)) * 2);
}

__device__ __forceinline__ void read_a(f16x8 (&d)[4][2], const f16* base, int q,
                                       int wm, int l15, int l4) {
#pragma unroll
  for (int mf = 0; mf < 4; ++mf)
#pragma unroll
    for (int kk = 0; kk < 2; ++kk) {
      int row = wm * 128 + (q * 4 + mf) * 16 + l15;
      int sl = kk * 4 + l4;
      d[mf][kk] = *(const f16x8*)(base + row * 64 + ((sl ^ (row & 7)) << 3));
    }
}

__device__ __forceinline__ void read_b2(f16x8 (&d)[2][2], const f16* base, int nh,
                                        int wn, int l15, int l4) {
#pragma unroll
  for (int nf = 0; nf < 2; ++nf)
#pragma unroll
    for (int kk = 0; kk < 2; ++kk) {
      int row = wn * 64 + (nh * 2 + nf) * 16 + l15;
      int sl = kk * 4 + l4;
      d[nf][kk] = *(const f16x8*)(base + row * 64 + ((sl ^ (row & 7)) << 3));
    }
}

__device__ __forceinline__ void read_b1(f16x8 (&d)[2], const f16* base, int f,
                                        int wn, int l15, int l4) {
#pragma unroll
  for (int kk = 0; kk < 2; ++kk) {
    int row = wn * 32 + f * 16 + l15;
    int sl = kk * 4 + l4;
    d[kk] = *(const f16x8*)(base + row * 64 + ((sl ^ (row & 7)) << 3));
  }
}

__device__ __forceinline__ void mfma_q(f32x4 (&acc)[8][4], const f16x8 (&Af)[4][2],
                                       const f16x8 (&Bf)[2][2], int q, int nh) {
#pragma unroll
  for (int mf = 0; mf < 4; ++mf)
#pragma unroll
    for (int nf = 0; nf < 2; ++nf)
#pragma unroll
      for (int kk = 0; kk < 2; ++kk)
        acc[q * 4 + mf][nh * 2 + nf] = __builtin_amdgcn_mfma_f32_16x16x32_f16(
            Af[mf][kk], Bf[nf][kk], acc[q * 4 + mf][nh * 2 + nf], 0, 0, 0);
}

__device__ __forceinline__ void mfma_n(f32x4 (&acc)[8][2], const f16x8 (&Af)[4][2],
                                       const f16x8 (&Bf)[2], int q, int f) {
#pragma unroll
  for (int mf = 0; mf < 4; ++mf)
#pragma unroll
    for (int kk = 0; kk < 2; ++kk)
      acc[q * 4 + mf][f] = __builtin_amdgcn_mfma_f32_16x16x32_f16(
          Af[mf][kk], Bf[kk], acc[q * 4 + mf][f], 0, 0, 0);
}

// ---------- 256x256 8-phase core (R3-verified gate discipline) ----------
__device__ __forceinline__ void g256_core(f32x4 (&acc)[8][4], const f16* Ag,
                                          const f16* Bg, long L, int NT,
                                          f16* lds, int tid, int wm, int wn,
                                          int l15, int l4) {
  f16* As0 = lds;
  f16* As1 = lds + 16384;
  f16* Bs0 = lds + 32768;
  f16* Bs1 = lds + 49152;
  f16x8 a[4][2], b[2][2], b2[2][2];
  const int NIT = NT >> 1;

#pragma unroll
  for (int h = 0; h < 4; ++h) stage64(Bg, L, Bs0, h, tid);
#pragma unroll
  for (int h = 0; h < 4; ++h) stage64(Ag, L, As0, h, tid);
#pragma unroll
  for (int h = 0; h < 4; ++h) stage64(Bg + 64, L, Bs1, h, tid);
#pragma unroll
  for (int h = 0; h < 4; ++h) stage64(Ag + 64, L, As1, h, tid);
  WAITV8();
  BAR();

  for (int i = 0; i < NIT; ++i) {
    int t2 = 2 * i + 2, t3 = 2 * i + 3;
    long k2 = (long)((t2 < NT) ? t2 : NT - 1) << 6;
    long k3 = (long)((t3 < NT) ? t3 : NT - 1) << 6;
    read_a(a, As0, 0, wm, l15, l4);
    read_b2(b, Bs0, 0, wn, l15, l4);
    BAR(); PRIO1(); mfma_q(acc, a, b, 0, 0); PRIO0(); BAR();
    read_b2(b2, Bs0, 1, wn, l15, l4);
    BAR(); PRIO1(); mfma_q(acc, a, b2, 0, 1); PRIO0(); BAR();
    read_a(a, As0, 1, wm, l15, l4);
    stage64(Bg + k2, L, Bs0, 0, tid); stage64(Bg + k2, L, Bs0, 1, tid);
    BAR(); PRIO1(); mfma_q(acc, a, b2, 1, 1); PRIO0(); BAR();
    stage64(Bg + k2, L, Bs0, 2, tid); stage64(Bg + k2, L, Bs0, 3, tid);
    BAR(); PRIO1(); mfma_q(acc, a, b, 1, 0); PRIO0();
    WAITV4();
    BAR();
    read_a(a, As1, 0, wm, l15, l4);
    read_b2(b, Bs1, 0, wn, l15, l4);
    stage64(Ag + k2, L, As0, 0, tid); stage64(Ag + k2, L, As0, 1, tid);
    BAR(); PRIO1(); mfma_q(acc, a, b, 0, 0); PRIO0(); BAR();
    read_b2(b2, Bs1, 1, wn, l15, l4);
    stage64(Ag + k2, L, As0, 2, tid); stage64(Ag + k2, L, As0, 3, tid);
    BAR(); PRIO1(); mfma_q(acc, a, b2, 0, 1); PRIO0(); BAR();
    read_a(a, As1, 1, wm, l15, l4);
    stage64(Bg + k3, L, Bs1, 0, tid); stage64(Bg + k3, L, Bs1, 1, tid);
    BAR(); PRIO1(); mfma_q(acc, a, b2, 1, 1); PRIO0(); BAR();
    stage64(Bg + k3, L, Bs1, 2, tid); stage64(Bg + k3, L, Bs1, 3, tid);
    stage64(Ag + k3, L, As1, 0, tid); stage64(Ag + k3, L, As1, 1, tid);
    stage64(Ag + k3, L, As1, 2, tid); stage64(Ag + k3, L, As1, 3, tid);
    BAR(); PRIO1(); mfma_q(acc, a, b, 1, 0); PRIO0();
    WAITV8();
    BAR();
  }
  WAITV0();
}

// ---------- 256x128 core (R6-verified, for PV) ----------
__device__ __forceinline__ void n128_core(f32x4 (&acc)[8][2], const f16* Ag,
                                          const f16* Bg, long L, int NT,
                                          f16* lds, int tid, int wm, int wn,
                                          int l15, int l4) {
  f16* As0 = lds;
  f16* As1 = lds + 16384;
  f16* Bs0 = lds + 32768;
  f16* Bs1 = lds + 40960;
  f16x8 a[4][2], b[2], b2[2];
  const int NIT = NT >> 1;

  stage64(Bg, L, Bs0, 0, tid); stage64(Bg, L, Bs0, 1, tid);
#pragma unroll
  for (int h = 0; h < 4; ++h) stage64(Ag, L, As0, h, tid);
  stage64(Bg + 64, L, Bs1, 0, tid); stage64(Bg + 64, L, Bs1, 1, tid);
#pragma unroll
  for (int h = 0; h < 4; ++h) stage64(Ag + 64, L, As1, h, tid);
  WAITV6();
  BAR();

  for (int i = 0; i < NIT; ++i) {
    int t2 = 2 * i + 2, t3 = 2 * i + 3;
    long k2 = (long)((t2 < NT) ? t2 : NT - 1) << 6;
    long k3 = (long)((t3 < NT) ? t3 : NT - 1) << 6;
    read_a(a, As0, 0, wm, l15, l4);
    read_b1(b, Bs0, 0, wn, l15, l4);
    BAR(); PRIO1(); mfma_n(acc, a, b, 0, 0); PRIO0(); BAR();
    read_b1(b2, Bs0, 1, wn, l15, l4);
    BAR(); PRIO1(); mfma_n(acc, a, b2, 0, 1); PRIO0(); BAR();
    read_a(a, As0, 1, wm, l15, l4);
    stage64(Bg + k2, L, Bs0, 0, tid); stage64(Bg + k2, L, Bs0, 1, tid);
    BAR(); PRIO1(); mfma_n(acc, a, b2, 1, 1); PRIO0(); BAR();
#pragma unroll
    for (int h = 0; h < 4; ++h) stage64(Ag + k2, L, As0, h, tid);
    BAR(); PRIO1(); mfma_n(acc, a, b, 1, 0); PRIO0();
    WAITV6();
    BAR();
    read_a(a, As1, 0, wm, l15, l4);
    read_b1(b, Bs1, 0, wn, l15, l4);
    BAR(); PRIO1(); mfma_n(acc, a, b, 0, 0); PRIO0(); BAR();
    read_b1(b2, Bs1, 1, wn, l15, l4);
    BAR(); PRIO1(); mfma_n(acc, a, b2, 0, 1); PRIO0(); BAR();
    read_a(a, As1, 1, wm, l15, l4);
    stage64(Bg + k3, L, Bs1, 0, tid); stage64(Bg + k3, L, Bs1, 1, tid);
    BAR(); PRIO1(); mfma_n(acc, a, b2, 1, 1); PRIO0(); BAR();
#pragma unroll
    for (int h = 0; h < 4; ++h) stage64(Ag + k3, L, As1, h, tid);
    BAR(); PRIO1(); mfma_n(acc, a, b, 1, 0); PRIO0();
    WAITV6();
    BAR();
  }
  WAITV0();
}

// ---------- uber: persistent QK+WV, 256^2 items, XCD-local (no deps) ----------
__global__ __launch_bounds__(512, 1) void uber(const f16* __restrict__ Qh,
                                               const f16* __restrict__ Kc,
                                               const f16* __restrict__ Vc,
                                               const f16* __restrict__ Wh,
                                               f16* __restrict__ P,
                                               f16* __restrict__ VWt,
                                               float* __restrict__ rowsum,
                                               const int2* __restrict__ cnt,
                                               const int* __restrict__ items,
                                               const int* __restrict__ nit) {
  extern __shared__ f16 lds[];
  const int tid = threadIdx.x;
  const int lane = tid & 63, wv = tid >> 6;
  const int wm = wv >> 2, wn = wv & 3;
  const int l15 = lane & 15, l4 = lane >> 4;
  const int n = nit[0];

  for (int idx = blockIdx.x; idx < n; idx += 256) {
    const int it = items[idx];
    const int kind = (it >> 24) & 3;
    if (kind == 3) continue;
    const int bx = it & 255, by = (it >> 8) & 255, bz = (it >> 16) & 255;
    const long m0 = (long)by * 256;
    const long n0 = (long)bx * 256;
    const f16* Ag = kind ? (Wh + m0 * EE) : (Qh + (long)bz * SS * EE + m0 * EE);
    const f16* Bg = (kind ? Vc : Kc) + (long)bz * SS * EE + n0 * EE;

    f32x4 acc[8][4] = {};
    g256_core(acc, Ag, Bg, EE, EE >> 6, lds, tid, wm, wn, l15, l4);

    const long crow = m0 + wm * 128 + l4 * 4;
    const long ccol = n0 + wn * 64 + l15;
    if (kind == 0) {
      const int count = cnt[bz].x;
      f16* Co = P + (long)bz * SS * SS;
      float* rs = rowsum + (bz << 11);
      const float scale = 1.0f / 32.0f;
      int mv[4];
#pragma unroll
      for (int nf = 0; nf < 4; ++nf) mv[nf] = (ccol + nf * 16) < count;
#pragma unroll
      for (int mf = 0; mf < 8; ++mf)
#pragma unroll
        for (int jj = 0; jj < 4; ++jj) {
          float rp = 0.f;
#pragma unroll
          for (int nf = 0; nf < 4; ++nf) {
            float p = mv[nf] ? __expf(acc[mf][nf][jj] * scale) : 0.f;
            Co[(crow + mf * 16 + jj) * SS + ccol + nf * 16] = (f16)p;
            rp += p;
          }
          rp += __shfl_xor(rp, 1); rp += __shfl_xor(rp, 2);
          rp += __shfl_xor(rp, 4); rp += __shfl_xor(rp, 8);
          if (l15 == 0) atomicAdd(&rs[crow + mf * 16 + jj], rp);
        }
    } else {
      f16* Co = VWt + (long)bz * EE * SS;
#pragma unroll
      for (int mf = 0; mf < 8; ++mf)
#pragma unroll
        for (int nf = 0; nf < 4; ++nf)
#pragma unroll
          for (int jj = 0; jj < 4; ++jj)
            Co[(crow + mf * 16 + jj) * SS + ccol + nf * 16] = (f16)acc[mf][nf][jj];
    }
  }
}

// ---------- PV: out = (P' @ VWt^T) / rowsum + bias (f32), 256x128 ----------
// Analytic XCD-local decode: XCD x = d&7 owns bz = x>>1, by-half = x&1.
__global__ __launch_bounds__(512, 1) void pv128(const f16* __restrict__ P,
                                                const f16* __restrict__ VWt,
                                                float* __restrict__ out,
                                                const float* __restrict__ bias,
                                                const float* __restrict__ rowsum,
                                                const int2* __restrict__ cnt) {
  extern __shared__ f16 lds[];
  const int d = blockIdx.x;  // 256 linear
  const int x = d & 7, r = d >> 3;
  const int bz = x >> 1;
  const int by = (x & 1) * 4 + (r & 3);
  const int bx = r >> 2;  // E-panel 0..7
  int2 cc = cnt[bz];
  const int padded = cc.y;
  if (padded <= 0) return;  // never taken; forces cnt-load wait before staging
  const long m0 = (long)by * 256;
  const long n0 = (long)bx * 128;
  const int tid = threadIdx.x;
  const int lane = tid & 63, wv = tid >> 6;
  const int wm = wv >> 2, wn = wv & 3;
  const int l15 = lane & 15, l4 = lane >> 4;
  const f16* Ag = P + (long)bz * SS * SS + m0 * SS;
  const f16* Bg = VWt + (long)bz * EE * SS + n0 * SS;

  f32x4 acc[8][2] = {};
  n128_core(acc, Ag, Bg, SS, padded >> 6, lds, tid, wm, wn, l15, l4);

  const long crow = m0 + wm * 128 + l4 * 4;
  const long ccol = n0 + wn * 32 + l15;
  float* Co = out + (long)bz * SS * EE;
  const float* rs = rowsum + (bz << 11);
  float bv[2];
#pragma unroll
  for (int nf = 0; nf < 2; ++nf) bv[nf] = bias[ccol + nf * 16];
#pragma unroll
  for (int mf = 0; mf < 8; ++mf)
#pragma unroll
    for (int jj = 0; jj < 4; ++jj) {
      float inv = 1.f / rs[crow + mf * 16 + jj];
#pragma unroll
      for (int nf = 0; nf < 2; ++nf)
        Co[(crow + mf * 16 + jj) * EE + ccol + nf * 16] =
            acc[mf][nf][jj] * inv + bv[nf];
    }
}

extern "C" void kernel_launch(void* const* d_in, const int* in_sizes, int n_in,
                              void* d_out, int out_size, void* d_ws, size_t ws_size,
                              hipStream_t stream) {
  const float* V = (const float*)d_in[0];
  const float* Kin = (const float*)d_in[1];
  const float* Q = (const float*)d_in[2];
  const int* mask = (const int*)d_in[3];
  const float* W = (const float*)d_in[4];
  const float* bias = (const float*)d_in[5];
  float* out = (float*)d_out;

  const long NE = (long)BB * SS * EE;  // 8388608
  f16* Qh = (f16*)d_ws;                  // NE
  f16* Kc = Qh + NE;                     // NE
  f16* Vc = Kc + NE;                     // NE
  f16* Wh = Vc + NE;                     // EE*EE
  f16* VWt = Wh + (long)EE * EE;         // NE ([B][E][S] stride SS)
  f16* P = VWt + NE;                     // 2*NE ([B][S][S] stride SS)
  float* rowsum = (float*)(P + (long)BB * SS * SS);  // B*S
  int* pos = (int*)(rowsum + (long)BB * SS);         // B*S
  int2* cnt = (int2*)(pos + (long)BB * SS);          // B
  int* items = (int*)(cnt + BB);                     // <=1024
  int* nit = items + 1024;                           // 1

  const size_t LDS_Q = 131072, LDS_N = 98304;
  hipFuncSetAttribute((const void*)uber, hipFuncAttributeMaxDynamicSharedMemorySize, LDS_Q);
  hipFuncSetAttribute((const void*)pv128, hipFuncAttributeMaxDynamicSharedMemorySize, LDS_N);

  prep<<<BB, 256, 0, stream>>>(mask, pos, cnt, Kc, Vc);
  prep2<<<4610 + BB * SS, 256, 0, stream>>>(Q, W, Kin, V, mask, pos, cnt,
                                            Qh, Wh, Kc, Vc, rowsum, items, nit);
  uber<<<256, 512, LDS_Q, stream>>>(Qh, Kc, Vc, Wh, P, VWt, rowsum, cnt, items, nit);
  pv128<<<256, 512, LDS_N, stream>>>(P, VWt, out, bias, rowsum, cnt);
}

// Round 10
// 91.663 us; speedup vs baseline: 2.8757x; 1.0646x over previous
//
#include <hip/hip_runtime.h>

#define BB 4
#define SS 2048
#define EE 1024

typedef _Float16 f16;
typedef _Float16 f16x4 __attribute__((ext_vector_type(4)));
typedef _Float16 f16x8 __attribute__((ext_vector_type(8)));
typedef float f32x4 __attribute__((ext_vector_type(4)));

typedef const __attribute__((address_space(1))) void* gas_ptr;
typedef __attribute__((address_space(3))) void* las_ptr;

__device__ __forceinline__ void gl_lds16(const void* g, void* l) {
  __builtin_amdgcn_global_load_lds((gas_ptr)g, (las_ptr)l, 16, 0, 0);
}

#define BAR() __builtin_amdgcn_s_barrier()
#define PRIO1() __builtin_amdgcn_s_setprio(1)
#define PRIO0() __builtin_amdgcn_s_setprio(0)
#define WAITV8() asm volatile("s_waitcnt vmcnt(8)" ::: "memory")
#define WAITV6() asm volatile("s_waitcnt vmcnt(6)" ::: "memory")
#define WAITV4() asm volatile("s_waitcnt vmcnt(4)" ::: "memory")
#define WAITV0() asm volatile("s_waitcnt vmcnt(0)" ::: "memory")

// ---------- prep: per-batch mask prefix-scan + pad-row zeroing (128-granular) ----------
__global__ __launch_bounds__(256) void prep(const int* __restrict__ mask,
                                            int* __restrict__ pos,
                                            int2* __restrict__ cnt,
                                            f16* __restrict__ Kc,
                                            f16* __restrict__ Vc) {
  const int b = blockIdx.x, t = threadIdx.x;
  const int* mb = mask + b * SS;
  int4 a0 = ((const int4*)mb)[t * 2];
  int4 a1 = ((const int4*)mb)[t * 2 + 1];
  int m[8] = {a0.x, a0.y, a0.z, a0.w, a1.x, a1.y, a1.z, a1.w};
  int tot = 0;
#pragma unroll
  for (int j = 0; j < 8; ++j) tot += m[j];
  __shared__ int sc[256];
  sc[t] = tot;
  __syncthreads();
  for (int off = 1; off < 256; off <<= 1) {
    int v = (t >= off) ? sc[t - off] : 0;
    __syncthreads();
    sc[t] += v;
    __syncthreads();
  }
  const int count = sc[255];
  const int padded = (count + 127) & ~127;  // 128-gran: pv K floor
  int run = sc[t] - tot;  // exclusive prefix
#pragma unroll
  for (int j = 0; j < 8; ++j) {
    pos[b * SS + t * 8 + j] = run;
    run += m[j];
  }
  if (t == 0) cnt[b] = make_int2(count, padded);
  const int nz = (padded - count) * 128;
  f16x8 z = {};
  for (int i = t; i < nz; i += 256) {
    int r = count + (i >> 7), cc = i & 127;
    ((f16x8*)(Kc + ((long)b * SS + r) * EE))[cc] = z;
    ((f16x8*)(Vc + ((long)b * SS + r) * EE))[cc] = z;
  }
}

// ---------- prep2: XCD-pinned Q cvt + W cvt + rowsum zero + list build + gather ----------
// Q-cvt block for panel(bz,by) runs on XCD 2bz+(by>>2) (its uber consumer).
// gather row (b,s) runs on XCD 2b+(s&1) (parity-split across the 2 consumers).
__global__ __launch_bounds__(256) void prep2(const float* __restrict__ Q,
                                             const float* __restrict__ W,
                                             const float* __restrict__ K,
                                             const float* __restrict__ V,
                                             const int* __restrict__ mask,
                                             const int* __restrict__ pos,
                                             const int2* __restrict__ cnt,
                                             f16* __restrict__ Qh,
                                             f16* __restrict__ Wh,
                                             f16* __restrict__ Kc,
                                             f16* __restrict__ Vc,
                                             float* __restrict__ rowsum,
                                             int* __restrict__ items,
                                             int* __restrict__ nit) {
  const int x = blockIdx.x, t = threadIdx.x;
  if (x < 4096) {  // Q cvt, hole-free XCD-pinned remap (x%8 = consumer XCD)
    const int e = x & 7, k = x >> 3;
    const int bz = e >> 1, half = e & 1, q = k >> 7, off = k & 127;
    const long logical = (long)((bz * 8 + half * 4 + q) << 7) + off;
    long i = logical * 256 + t;
    float4 v0 = ((const float4*)Q)[i * 2];
    float4 v1 = ((const float4*)Q)[i * 2 + 1];
    f16x8 o;
    o[0] = (f16)v0.x; o[1] = (f16)v0.y; o[2] = (f16)v0.z; o[3] = (f16)v0.w;
    o[4] = (f16)v1.x; o[5] = (f16)v1.y; o[6] = (f16)v1.z; o[7] = (f16)v1.w;
    ((f16x8*)Qh)[i] = o;
    return;
  }
  if (x < 4608) {  // W cvt
    long i = (long)(x - 4096) * 256 + t;
    float4 v0 = ((const float4*)W)[i * 2];
    float4 v1 = ((const float4*)W)[i * 2 + 1];
    f16x8 o;
    o[0] = (f16)v0.x; o[1] = (f16)v0.y; o[2] = (f16)v0.z; o[3] = (f16)v0.w;
    o[4] = (f16)v1.x; o[5] = (f16)v1.y; o[6] = (f16)v1.z; o[7] = (f16)v1.w;
    ((f16x8*)Wh)[i] = o;
    return;
  }
  if (x == 4608) {  // zero rowsum[B*S]
    float4 z = {0.f, 0.f, 0.f, 0.f};
#pragma unroll
    for (int r = 0; r < 8; ++r) ((float4*)rowsum)[t + r * 256] = z;
    return;
  }
  if (x == 4609) {  // item list (256-wide tiles over 128-gran padding)
    if (t < 8) {
      int nbx[4];
#pragma unroll
      for (int zz = 0; zz < 4; ++zz) nbx[zz] = (cnt[zz].y + 255) >> 8;
      int mxn = nbx[0];
#pragma unroll
      for (int zz = 1; zz < 4; ++zz) mxn = nbx[zz] > mxn ? nbx[zz] : mxn;
      const int mx = 6 * mxn;
      const int bz = t >> 1, half = t & 1;
      int g = 0;
      for (int q = 0; q < 4; ++q)
        for (int bx = 0; bx < nbx[bz]; ++bx)
          items[(g++ << 3) | t] = bx | ((half * 4 + q) << 8) | (bz << 16);
      for (int q = 0; q < 2; ++q)
        for (int bx = 0; bx < nbx[bz]; ++bx)
          items[(g++ << 3) | t] = bx | ((half * 2 + q) << 8) | (bz << 16) | (1 << 24);
      for (; g < mx; ++g) items[(g << 3) | t] = (3 << 24);
      if (t == 0) nit[0] = mx << 3;
    }
    return;
  }
  // gather, hole-free XCD-pinned: blockIdx%8 = (g+2)&7 = 2b+(s&1)
  const int g = x - 4610;
  const int e = (g + 2) & 7;  // (4610+g)%8, 4610%8==2
  const int b = e >> 1;
  const int s = ((g >> 3) << 1) | (e & 1);
  if (!mask[b * SS + s]) return;
  const int p = pos[b * SS + s];
  float4 kv = ((const float4*)(K + ((long)b * SS + s) * EE))[t];
  float4 vv = ((const float4*)(V + ((long)b * SS + s) * EE))[t];
  f16x4 ko, vo;
  ko[0] = (f16)kv.x; ko[1] = (f16)kv.y; ko[2] = (f16)kv.z; ko[3] = (f16)kv.w;
  vo[0] = (f16)vv.x; vo[1] = (f16)vv.y; vo[2] = (f16)vv.z; vo[3] = (f16)vv.w;
  ((f16x4*)(Kc + ((long)b * SS + p) * EE))[t] = ko;
  ((f16x4*)(Vc + ((long)b * SS + p) * EE))[t] = vo;
}

// ---------- shared staging / read helpers (swizzle: slot ^= row&7) ----------
__device__ __forceinline__ void stage64(const f16* g, long K, f16* l, int h, int t) {
  int rr = t >> 3, sp = t & 7;
  int row = h * 64 + rr;
  int sl = sp ^ (rr & 7);
  gl_lds16(g + (long)row * K + (sl << 3), (char*)l + ((row << 6) + (sp << 3)) * 2);
}

__device__ __forceinline__ void read_a(f16x8 (&d)[4][2], const f16* base, int q,
                                       int wm, int l15, int l4) {
#pragma unroll
  for (int mf = 0; mf < 4; ++mf)
#pragma unroll
    for (int kk = 0; kk < 2; ++kk) {
      int row = wm * 128 + (q * 4 + mf) * 16 + l15;
      int sl = kk * 4 + l4;
      d[mf][kk] = *(const f16x8*)(base + row * 64 + ((sl ^ (row & 7)) << 3));
    }
}

__device__ __forceinline__ void read_b2(f16x8 (&d)[2][2], const f16* base, int nh,
                                        int wn, int l15, int l4) {
#pragma unroll
  for (int nf = 0; nf < 2; ++nf)
#pragma unroll
    for (int kk = 0; kk < 2; ++kk) {
      int row = wn * 64 + (nh * 2 + nf) * 16 + l15;
      int sl = kk * 4 + l4;
      d[nf][kk] = *(const f16x8*)(base + row * 64 + ((sl ^ (row & 7)) << 3));
    }
}

__device__ __forceinline__ void read_b1(f16x8 (&d)[2], const f16* base, int f,
                                        int wn, int l15, int l4) {
#pragma unroll
  for (int kk = 0; kk < 2; ++kk) {
    int row = wn * 32 + f * 16 + l15;
    int sl = kk * 4 + l4;
    d[kk] = *(const f16x8*)(base + row * 64 + ((sl ^ (row & 7)) << 3));
  }
}

__device__ __forceinline__ void mfma_q(f32x4 (&acc)[8][4], const f16x8 (&Af)[4][2],
                                       const f16x8 (&Bf)[2][2], int q, int nh) {
#pragma unroll
  for (int mf = 0; mf < 4; ++mf)
#pragma unroll
    for (int nf = 0; nf < 2; ++nf)
#pragma unroll
      for (int kk = 0; kk < 2; ++kk)
        acc[q * 4 + mf][nh * 2 + nf] = __builtin_amdgcn_mfma_f32_16x16x32_f16(
            Af[mf][kk], Bf[nf][kk], acc[q * 4 + mf][nh * 2 + nf], 0, 0, 0);
}

__device__ __forceinline__ void mfma_n(f32x4 (&acc)[8][2], const f16x8 (&Af)[4][2],
                                       const f16x8 (&Bf)[2], int q, int f) {
#pragma unroll
  for (int mf = 0; mf < 4; ++mf)
#pragma unroll
    for (int kk = 0; kk < 2; ++kk)
      acc[q * 4 + mf][f] = __builtin_amdgcn_mfma_f32_16x16x32_f16(
          Af[mf][kk], Bf[kk], acc[q * 4 + mf][f], 0, 0, 0);
}

// ---------- 256x256 8-phase core (R3-verified gate discipline) ----------
__device__ __forceinline__ void g256_core(f32x4 (&acc)[8][4], const f16* Ag,
                                          const f16* Bg, long L, int NT,
                                          f16* lds, int tid, int wm, int wn,
                                          int l15, int l4) {
  f16* As0 = lds;
  f16* As1 = lds + 16384;
  f16* Bs0 = lds + 32768;
  f16* Bs1 = lds + 49152;
  f16x8 a[4][2], b[2][2], b2[2][2];
  const int NIT = NT >> 1;

#pragma unroll
  for (int h = 0; h < 4; ++h) stage64(Bg, L, Bs0, h, tid);
#pragma unroll
  for (int h = 0; h < 4; ++h) stage64(Ag, L, As0, h, tid);
#pragma unroll
  for (int h = 0; h < 4; ++h) stage64(Bg + 64, L, Bs1, h, tid);
#pragma unroll
  for (int h = 0; h < 4; ++h) stage64(Ag + 64, L, As1, h, tid);
  WAITV8();
  BAR();

  for (int i = 0; i < NIT; ++i) {
    int t2 = 2 * i + 2, t3 = 2 * i + 3;
    long k2 = (long)((t2 < NT) ? t2 : NT - 1) << 6;
    long k3 = (long)((t3 < NT) ? t3 : NT - 1) << 6;
    read_a(a, As0, 0, wm, l15, l4);
    read_b2(b, Bs0, 0, wn, l15, l4);
    BAR(); PRIO1(); mfma_q(acc, a, b, 0, 0); PRIO0(); BAR();
    read_b2(b2, Bs0, 1, wn, l15, l4);
    BAR(); PRIO1(); mfma_q(acc, a, b2, 0, 1); PRIO0(); BAR();
    read_a(a, As0, 1, wm, l15, l4);
    stage64(Bg + k2, L, Bs0, 0, tid); stage64(Bg + k2, L, Bs0, 1, tid);
    BAR(); PRIO1(); mfma_q(acc, a, b2, 1, 1); PRIO0(); BAR();
    stage64(Bg + k2, L, Bs0, 2, tid); stage64(Bg + k2, L, Bs0, 3, tid);
    BAR(); PRIO1(); mfma_q(acc, a, b, 1, 0); PRIO0();
    WAITV4();
    BAR();
    read_a(a, As1, 0, wm, l15, l4);
    read_b2(b, Bs1, 0, wn, l15, l4);
    stage64(Ag + k2, L, As0, 0, tid); stage64(Ag + k2, L, As0, 1, tid);
    BAR(); PRIO1(); mfma_q(acc, a, b, 0, 0); PRIO0(); BAR();
    read_b2(b2, Bs1, 1, wn, l15, l4);
    stage64(Ag + k2, L, As0, 2, tid); stage64(Ag + k2, L, As0, 3, tid);
    BAR(); PRIO1(); mfma_q(acc, a, b2, 0, 1); PRIO0(); BAR();
    read_a(a, As1, 1, wm, l15, l4);
    stage64(Bg + k3, L, Bs1, 0, tid); stage64(Bg + k3, L, Bs1, 1, tid);
    BAR(); PRIO1(); mfma_q(acc, a, b2, 1, 1); PRIO0(); BAR();
    stage64(Bg + k3, L, Bs1, 2, tid); stage64(Bg + k3, L, Bs1, 3, tid);
    stage64(Ag + k3, L, As1, 0, tid); stage64(Ag + k3, L, As1, 1, tid);
    stage64(Ag + k3, L, As1, 2, tid); stage64(Ag + k3, L, As1, 3, tid);
    BAR(); PRIO1(); mfma_q(acc, a, b, 1, 0); PRIO0();
    WAITV8();
    BAR();
  }
  WAITV0();
}

// ---------- 256x128 core (R6-verified, for PV) ----------
__device__ __forceinline__ void n128_core(f32x4 (&acc)[8][2], const f16* Ag,
                                          const f16* Bg, long L, int NT,
                                          f16* lds, int tid, int wm, int wn,
                                          int l15, int l4) {
  f16* As0 = lds;
  f16* As1 = lds + 16384;
  f16* Bs0 = lds + 32768;
  f16* Bs1 = lds + 40960;
  f16x8 a[4][2], b[2], b2[2];
  const int NIT = NT >> 1;

  stage64(Bg, L, Bs0, 0, tid); stage64(Bg, L, Bs0, 1, tid);
#pragma unroll
  for (int h = 0; h < 4; ++h) stage64(Ag, L, As0, h, tid);
  stage64(Bg + 64, L, Bs1, 0, tid); stage64(Bg + 64, L, Bs1, 1, tid);
#pragma unroll
  for (int h = 0; h < 4; ++h) stage64(Ag + 64, L, As1, h, tid);
  WAITV6();
  BAR();

  for (int i = 0; i < NIT; ++i) {
    int t2 = 2 * i + 2, t3 = 2 * i + 3;
    long k2 = (long)((t2 < NT) ? t2 : NT - 1) << 6;
    long k3 = (long)((t3 < NT) ? t3 : NT - 1) << 6;
    read_a(a, As0, 0, wm, l15, l4);
    read_b1(b, Bs0, 0, wn, l15, l4);
    BAR(); PRIO1(); mfma_n(acc, a, b, 0, 0); PRIO0(); BAR();
    read_b1(b2, Bs0, 1, wn, l15, l4);
    BAR(); PRIO1(); mfma_n(acc, a, b2, 0, 1); PRIO0(); BAR();
    read_a(a, As0, 1, wm, l15, l4);
    stage64(Bg + k2, L, Bs0, 0, tid); stage64(Bg + k2, L, Bs0, 1, tid);
    BAR(); PRIO1(); mfma_n(acc, a, b2, 1, 1); PRIO0(); BAR();
#pragma unroll
    for (int h = 0; h < 4; ++h) stage64(Ag + k2, L, As0, h, tid);
    BAR(); PRIO1(); mfma_n(acc, a, b, 1, 0); PRIO0();
    WAITV6();
    BAR();
    read_a(a, As1, 0, wm, l15, l4);
    read_b1(b, Bs1, 0, wn, l15, l4);
    BAR(); PRIO1(); mfma_n(acc, a, b, 0, 0); PRIO0(); BAR();
    read_b1(b2, Bs1, 1, wn, l15, l4);
    BAR(); PRIO1(); mfma_n(acc, a, b2, 0, 1); PRIO0(); BAR();
    read_a(a, As1, 1, wm, l15, l4);
    stage64(Bg + k3, L, Bs1, 0, tid); stage64(Bg + k3, L, Bs1, 1, tid);
    BAR(); PRIO1(); mfma_n(acc, a, b2, 1, 1); PRIO0(); BAR();
#pragma unroll
    for (int h = 0; h < 4; ++h) stage64(Ag + k3, L, As1, h, tid);
    BAR(); PRIO1(); mfma_n(acc, a, b, 1, 0); PRIO0();
    WAITV6();
    BAR();
  }
  WAITV0();
}

// ---------- uber: persistent QK+WV, 256^2 items, XCD-local (no deps) ----------
__global__ __launch_bounds__(512, 1) void uber(const f16* __restrict__ Qh,
                                               const f16* __restrict__ Kc,
                                               const f16* __restrict__ Vc,
                                               const f16* __restrict__ Wh,
                                               f16* __restrict__ P,
                                               f16* __restrict__ VWt,
                                               float* __restrict__ rowsum,
                                               const int2* __restrict__ cnt,
                                               const int* __restrict__ items,
                                               const int* __restrict__ nit) {
  extern __shared__ f16 lds[];
  const int tid = threadIdx.x;
  const int lane = tid & 63, wv = tid >> 6;
  const int wm = wv >> 2, wn = wv & 3;
  const int l15 = lane & 15, l4 = lane >> 4;
  const int n = nit[0];

  for (int idx = blockIdx.x; idx < n; idx += 256) {
    const int it = items[idx];
    const int kind = (it >> 24) & 3;
    if (kind == 3) continue;
    const int bx = it & 255, by = (it >> 8) & 255, bz = (it >> 16) & 255;
    const long m0 = (long)by * 256;
    const long n0 = (long)bx * 256;
    const f16* Ag = kind ? (Wh + m0 * EE) : (Qh + (long)bz * SS * EE + m0 * EE);
    const f16* Bg = (kind ? Vc : Kc) + (long)bz * SS * EE + n0 * EE;

    f32x4 acc[8][4] = {};
    g256_core(acc, Ag, Bg, EE, EE >> 6, lds, tid, wm, wn, l15, l4);

    const long crow = m0 + wm * 128 + l4 * 4;
    const long ccol = n0 + wn * 64 + l15;
    if (kind == 0) {
      const int count = cnt[bz].x;
      f16* Co = P + (long)bz * SS * SS;
      float* rs = rowsum + (bz << 11);
      const float scale = 1.0f / 32.0f;
      int mv[4];
#pragma unroll
      for (int nf = 0; nf < 4; ++nf) mv[nf] = (ccol + nf * 16) < count;
#pragma unroll
      for (int mf = 0; mf < 8; ++mf)
#pragma unroll
        for (int jj = 0; jj < 4; ++jj) {
          float rp = 0.f;
#pragma unroll
          for (int nf = 0; nf < 4; ++nf) {
            float p = mv[nf] ? __expf(acc[mf][nf][jj] * scale) : 0.f;
            Co[(crow + mf * 16 + jj) * SS + ccol + nf * 16] = (f16)p;
            rp += p;
          }
          rp += __shfl_xor(rp, 1); rp += __shfl_xor(rp, 2);
          rp += __shfl_xor(rp, 4); rp += __shfl_xor(rp, 8);
          if (l15 == 0) atomicAdd(&rs[crow + mf * 16 + jj], rp);
        }
    } else {
      f16* Co = VWt + (long)bz * EE * SS;
#pragma unroll
      for (int mf = 0; mf < 8; ++mf)
#pragma unroll
        for (int nf = 0; nf < 4; ++nf)
#pragma unroll
          for (int jj = 0; jj < 4; ++jj)
            Co[(crow + mf * 16 + jj) * SS + ccol + nf * 16] = (f16)acc[mf][nf][jj];
    }
  }
}

// ---------- PV: out = (P' @ VWt^T) / rowsum + bias (f32), 256x128 ----------
// Analytic XCD-local decode: XCD x = d&7 owns bz = x>>1, by-half = x&1.
__global__ __launch_bounds__(512, 1) void pv128(const f16* __restrict__ P,
                                                const f16* __restrict__ VWt,
                                                float* __restrict__ out,
                                                const float* __restrict__ bias,
                                                const float* __restrict__ rowsum,
                                                const int2* __restrict__ cnt) {
  extern __shared__ f16 lds[];
  const int d = blockIdx.x;  // 256 linear
  const int x = d & 7, r = d >> 3;
  const int bz = x >> 1;
  const int by = (x & 1) * 4 + (r & 3);
  const int bx = r >> 2;  // E-panel 0..7
  int2 cc = cnt[bz];
  const int padded = cc.y;
  if (padded <= 0) return;  // never taken; forces cnt-load wait before staging
  const long m0 = (long)by * 256;
  const long n0 = (long)bx * 128;
  const int tid = threadIdx.x;
  const int lane = tid & 63, wv = tid >> 6;
  const int wm = wv >> 2, wn = wv & 3;
  const int l15 = lane & 15, l4 = lane >> 4;
  const f16* Ag = P + (long)bz * SS * SS + m0 * SS;
  const f16* Bg = VWt + (long)bz * EE * SS + n0 * SS;

  f32x4 acc[8][2] = {};
  n128_core(acc, Ag, Bg, SS, padded >> 6, lds, tid, wm, wn, l15, l4);

  const long crow = m0 + wm * 128 + l4 * 4;
  const long ccol = n0 + wn * 32 + l15;
  float* Co = out + (long)bz * SS * EE;
  const float* rs = rowsum + (bz << 11);
  float bv[2];
#pragma unroll
  for (int nf = 0; nf < 2; ++nf) bv[nf] = bias[ccol + nf * 16];
#pragma unroll
  for (int mf = 0; mf < 8; ++mf)
#pragma unroll
    for (int jj = 0; jj < 4; ++jj) {
      float inv = 1.f / rs[crow + mf * 16 + jj];
#pragma unroll
      for (int nf = 0; nf < 2; ++nf)
        Co[(crow + mf * 16 + jj) * EE + ccol + nf * 16] =
            acc[mf][nf][jj] * inv + bv[nf];
    }
}

extern "C" void kernel_launch(void* const* d_in, const int* in_sizes, int n_in,
                              void* d_out, int out_size, void* d_ws, size_t ws_size,
                              hipStream_t stream) {
  const float* V = (const float*)d_in[0];
  const float* Kin = (const float*)d_in[1];
  const float* Q = (const float*)d_in[2];
  const int* mask = (const int*)d_in[3];
  const float* W = (const float*)d_in[4];
  const float* bias = (const float*)d_in[5];
  float* out = (float*)d_out;

  const long NE = (long)BB * SS * EE;  // 8388608
  f16* Qh = (f16*)d_ws;                  // NE
  f16* Kc = Qh + NE;                     // NE
  f16* Vc = Kc + NE;                     // NE
  f16* Wh = Vc + NE;                     // EE*EE
  f16* VWt = Wh + (long)EE * EE;         // NE ([B][E][S] stride SS)
  f16* P = VWt + NE;                     // 2*NE ([B][S][S] stride SS)
  float* rowsum = (float*)(P + (long)BB * SS * SS);  // B*S
  int* pos = (int*)(rowsum + (long)BB * SS);         // B*S
  int2* cnt = (int2*)(pos + (long)BB * SS);          // B
  int* items = (int*)(cnt + BB);                     // <=1024
  int* nit = items + 1024;                           // 1

  const size_t LDS_Q = 131072, LDS_N = 98304;
  hipFuncSetAttribute((const void*)uber, hipFuncAttributeMaxDynamicSharedMemorySize, LDS_Q);
  hipFuncSetAttribute((const void*)pv128, hipFuncAttributeMaxDynamicSharedMemorySize, LDS_N);

  prep<<<BB, 256, 0, stream>>>(mask, pos, cnt, Kc, Vc);
  prep2<<<4610 + BB * SS, 256, 0, stream>>>(Q, W, Kin, V, mask, pos, cnt,
                                            Qh, Wh, Kc, Vc, rowsum, items, nit);
  uber<<<256, 512, LDS_Q, stream>>>(Qh, Kc, Vc, Wh, P, VWt, rowsum, cnt, items, nit);
  pv128<<<256, 512, LDS_N, stream>>>(P, VWt, out, bias, rowsum, cnt);
}